// Round 3
// baseline (366.574 us; speedup 1.0000x reference)
//
#include <hip/hip_runtime.h>
#include <hip/hip_cooperative_groups.h>

namespace cg = cooperative_groups;

// Problem constants (from reference)
#define N_NODES 4096
#define F_IN    128
#define UNITS   64
#define HEADS   4
#define ROWS_PB 4                      // rows per block (fused kernel)
#define GRID_F  (N_NODES / ROWS_PB)    // 1024 blocks = 4 blocks/CU on 256 CUs
#define NBR_CAP 160                    // per-row neighbor capacity (mean 41, sd 6.4 -> 18 sigma)
#define K2_CHUNK 256                   // legacy fallback path

// ---------------------------------------------------------------------------
// kzero: zero the S accumulator (64 floats) ahead of the fused kernel's
// global atomicAdds. Stream order guarantees completion before kfused.
// ---------------------------------------------------------------------------
__global__ void kzero(float* __restrict__ S) {
    if (threadIdx.x < UNITS) S[threadIdx.x] = 0.f;
}

// ---------------------------------------------------------------------------
// Fused cooperative kernel. 1024 blocks x 256 threads, 4 rows per block.
//
// Phase 0 (pre grid-sync):
//   - stage w (32 KB LDS, natural [k][u]: ds_read_b32 at bank=u%32, 2-way = free)
//   - scan own 4 adj rows (the 64-MiB HBM read — the irreducible cost),
//     ballot-compact neighbor ids into persistent LDS
//   - GEMM 4 rows of x (wave = row, lane = column), write x to global
//   - e1 -> LDS only (only this block ever needs it); e2 -> global
//   - column-sum partials -> global atomicAdd into S (device scope, XCD-safe)
// The adj scan overlaps the GEMM/e compute across the 4 resident blocks/CU —
// this is the overlap the 3-kernel pipeline could not express.
//
// grid.sync() with explicit agent-scope fences on both sides (per-XCD L2s are
// not cross-coherent; x/e2 written on one XCD are read from others in phase 1).
//
// Phase 1 (post grid-sync), per row:
//   - phase A: one thread per neighbor computes all 4 head weights (float4->LDS)
//   - phase B: 4 waves split the neighbor list; x row loaded once per block;
//     each lane carries 4 head accumulators; den accumulated wave-uniformly
//   - cross-wave LDS reduction, coalesced out write
//
// LDS: 32 KB overlay (w | phase-1 wgt/red) + in 2KB + x_lds 1KB + nbr 1.25KB
//      + e1loc/cnt ~ 37.2 KB -> 4 blocks/CU resident (cooperative-legal at 1024).
// ---------------------------------------------------------------------------
struct P1 {
    float4 wgt[NBR_CAP];            // per-neighbor head weights
    float  red[4][HEADS * UNITS];   // per-wave partial sums
    float4 denred[4];               // per-wave den partials
};

__global__ __launch_bounds__(256, 4) void kfused(
        const float* __restrict__ inputs, const float* __restrict__ adj,
        const float* __restrict__ w, const float* __restrict__ aw1,
        const float* __restrict__ aw2, float* __restrict__ x,
        float* __restrict__ e2g, float* __restrict__ S,
        float* __restrict__ out)
{
    __shared__ union { float wlds[F_IN * UNITS]; P1 p1; } ovl;  // 32 KB overlay
    __shared__ float in_lds[ROWS_PB * F_IN];                    // 2 KB
    __shared__ float x_lds[ROWS_PB * 65];                       // 1.04 KB (pad 65)
    __shared__ unsigned short nbr[ROWS_PB * NBR_CAP];           // 1.25 KB, persists
    __shared__ float4 e1loc[ROWS_PB];                           // e1 never hits global
    __shared__ int cntA[ROWS_PB];

    const int t    = threadIdx.x;
    const int b    = blockIdx.x;
    const int row0 = b * ROWS_PB;
    const int lane = t & 63;
    const int wid  = t >> 6;

    if (t < ROWS_PB) cntA[t] = 0;
    __syncthreads();

    // ---- stage w + input rows ----
    {
        const float4* src = (const float4*)w;
        float4* dst = (float4*)ovl.wlds;
        for (int idx = t; idx < F_IN * UNITS / 4; idx += 256) dst[idx] = src[idx];
    }
    if (t < ROWS_PB * F_IN / 4)
        ((float4*)in_lds)[t] = ((const float4*)(inputs + (size_t)row0 * F_IN))[t];

    // ---- adj scan + ballot compaction for this block's 4 rows ----
    const unsigned long long lt = (1ull << lane) - 1ull;
    for (int q = 0; q < ROWS_PB; q++) {
        const int nbase = q * NBR_CAP;
        const float4* arow = (const float4*)(adj + (size_t)(row0 + q) * N_NODES);
        const float4 v0 = arow[t];
        const float4 v1 = arow[t + 256];
        const float4 v2 = arow[t + 512];
        const float4 v3 = arow[t + 768];

        const unsigned long long b0  = __ballot(v0.x != 0.f);
        const unsigned long long b1  = __ballot(v0.y != 0.f);
        const unsigned long long b2  = __ballot(v0.z != 0.f);
        const unsigned long long b3  = __ballot(v0.w != 0.f);
        const unsigned long long b4  = __ballot(v1.x != 0.f);
        const unsigned long long b5  = __ballot(v1.y != 0.f);
        const unsigned long long b6  = __ballot(v1.z != 0.f);
        const unsigned long long b7  = __ballot(v1.w != 0.f);
        const unsigned long long b8  = __ballot(v2.x != 0.f);
        const unsigned long long b9  = __ballot(v2.y != 0.f);
        const unsigned long long b10 = __ballot(v2.z != 0.f);
        const unsigned long long b11 = __ballot(v2.w != 0.f);
        const unsigned long long b12 = __ballot(v3.x != 0.f);
        const unsigned long long b13 = __ballot(v3.y != 0.f);
        const unsigned long long b14 = __ballot(v3.z != 0.f);
        const unsigned long long b15 = __ballot(v3.w != 0.f);

        const int tot = __popcll(b0) + __popcll(b1) + __popcll(b2) + __popcll(b3)
                      + __popcll(b4) + __popcll(b5) + __popcll(b6) + __popcll(b7)
                      + __popcll(b8) + __popcll(b9) + __popcll(b10) + __popcll(b11)
                      + __popcll(b12) + __popcll(b13) + __popcll(b14) + __popcll(b15);

        int wbase = 0;
        if (lane == 0) wbase = atomicAdd(&cntA[q], tot);   // ONE atomic per wave
        wbase = __shfl(wbase, 0);

        int off = wbase;
        const int g0 = t * 4, g1 = (t + 256) * 4, g2 = (t + 512) * 4, g3 = (t + 768) * 4;
#define EMIT(val, bm, gidx) \
        do { if ((val) != 0.f) { const int p_ = off + __popcll((bm) & lt); \
             if (p_ < NBR_CAP) nbr[nbase + p_] = (unsigned short)(gidx); } \
             off += __popcll(bm); } while (0)
        EMIT(v0.x, b0,  g0 + 0); EMIT(v0.y, b1,  g0 + 1);
        EMIT(v0.z, b2,  g0 + 2); EMIT(v0.w, b3,  g0 + 3);
        EMIT(v1.x, b4,  g1 + 0); EMIT(v1.y, b5,  g1 + 1);
        EMIT(v1.z, b6,  g1 + 2); EMIT(v1.w, b7,  g1 + 3);
        EMIT(v2.x, b8,  g2 + 0); EMIT(v2.y, b9,  g2 + 1);
        EMIT(v2.z, b10, g2 + 2); EMIT(v2.w, b11, g2 + 3);
        EMIT(v3.x, b12, g3 + 0); EMIT(v3.y, b13, g3 + 1);
        EMIT(v3.z, b14, g3 + 2); EMIT(v3.w, b15, g3 + 3);
#undef EMIT
    }
    __syncthreads();   // staging + scan complete

    // ---- GEMM: wave wid -> row row0+wid, lane -> column ----
    {
        float acc = 0.f;
        const float4* ir = (const float4*)(in_lds + wid * F_IN);  // wave-uniform: broadcast
#pragma unroll 8
        for (int c = 0; c < F_IN / 4; c++) {
            const float4 a = ir[c];
            const int k4 = c * 4;
            acc = fmaf(a.x, ovl.wlds[(k4 + 0) * UNITS + lane],
                  fmaf(a.y, ovl.wlds[(k4 + 1) * UNITS + lane],
                  fmaf(a.z, ovl.wlds[(k4 + 2) * UNITS + lane],
                  fmaf(a.w, ovl.wlds[(k4 + 3) * UNITS + lane], acc))));
        }
        x_lds[wid * 65 + lane] = acc;
        x[(size_t)(row0 + wid) * UNITS + lane] = acc;
    }
    __syncthreads();   // x_lds complete

    // ---- e1 (LDS only) / e2 (global): 4 rows x 4 heads x 2 = 32 tasks ----
    if (t < 32) {
        const int r = t >> 3;
        const int rem = t & 7;
        const int h = rem & 3;
        const bool first = rem < 4;
        const float* aw = first ? aw1 : aw2;   // 1 KB each, L2-hot
        float s = 0.f;
#pragma unroll 8
        for (int uu = 0; uu < UNITS; uu++)
            s += x_lds[r * 65 + uu] * aw[uu * HEADS + h];
        if (first) ((float*)&e1loc[r])[h] = s;
        else       e2g[(size_t)(row0 + r) * HEADS + h] = s;
    }
    // ---- column-sum partials -> global S (device-scope atomics) ----
    if (t < 64) {
        const float s = x_lds[0 * 65 + t] + x_lds[1 * 65 + t]
                      + x_lds[2 * 65 + t] + x_lds[3 * 65 + t];
        atomicAdd(&S[t], s);
    }

    __threadfence();          // release: x/e2 visible beyond this XCD's L2
    cg::this_grid().sync();
    __threadfence();          // acquire: invalidate stale lines before remote reads

    const float Sv = S[lane];

    // ---- phase 1: per-row aggregation (round-2 wave-split structure) ----
    for (int q = 0; q < ROWS_PB; q++) {
        const int i = row0 + q;
        const int n = min(cntA[q], NBR_CAP);
        const float4 e1v = e1loc[q];

        // phase A: weights, one thread per neighbor (n < 256 always)
        if (t < n) {
            const int j = nbr[q * NBR_CAP + t];
            const float4 e2v = *(const float4*)(e2g + (size_t)j * HEADS);
            float4 wv;
            wv.x = __expf(fmaxf(e1v.x + e2v.x, 0.f)) - 1.f;
            wv.y = __expf(fmaxf(e1v.y + e2v.y, 0.f)) - 1.f;
            wv.z = __expf(fmaxf(e1v.z + e2v.z, 0.f)) - 1.f;
            wv.w = __expf(fmaxf(e1v.w + e2v.w, 0.f)) - 1.f;
            ovl.p1.wgt[t] = wv;
        }
        __syncthreads();

        // phase B: waves split the neighbor list; x row loaded once per block
        float a0 = 0.f, a1 = 0.f, a2 = 0.f, a3 = 0.f;
        float dx = 0.f, dy = 0.f, dz = 0.f, dw = 0.f;
        for (int k = wid; k < n; k += 4) {
            const float4 p = ovl.p1.wgt[k];             // broadcast ds_read_b128
            const int j = nbr[q * NBR_CAP + k];         // uniform LDS read
            const float xv = x[(j << 6) + lane];        // coalesced 256 B, L2/L3-hit
            a0 = fmaf(p.x, xv, a0);
            a1 = fmaf(p.y, xv, a1);
            a2 = fmaf(p.z, xv, a2);
            a3 = fmaf(p.w, xv, a3);
            dx += p.x; dy += p.y; dz += p.z; dw += p.w; // wave-uniform den partial
        }
        ovl.p1.red[wid][0 * 64 + lane] = a0;
        ovl.p1.red[wid][1 * 64 + lane] = a1;
        ovl.p1.red[wid][2 * 64 + lane] = a2;
        ovl.p1.red[wid][3 * 64 + lane] = a3;
        if (lane == 0) ovl.p1.denred[wid] = make_float4(dx, dy, dz, dw);
        __syncthreads();

        // reduce + write: thread t = (h=t>>6)*64 + (u=t&63) = t exactly
        const float accsum = ovl.p1.red[0][t] + ovl.p1.red[1][t]
                           + ovl.p1.red[2][t] + ovl.p1.red[3][t];
        const float den = ((const float*)&ovl.p1.denred[0])[wid]
                        + ((const float*)&ovl.p1.denred[1])[wid]
                        + ((const float*)&ovl.p1.denred[2])[wid]
                        + ((const float*)&ovl.p1.denred[3])[wid];
        out[(size_t)i * (HEADS * UNITS) + t] =
            fmaxf((Sv + accsum) / ((float)N_NODES + den), 0.f);
        // no trailing sync needed: next phase A writes wgt (disjoint from red),
        // and phase B of row q is fenced off by the post-A sync above.
    }
}

// ===========================================================================
// Legacy 3-kernel path (round-2, proven) — fallback if cooperative launch is
// rejected (e.g. unsupported under graph capture).
// ===========================================================================
__global__ __launch_bounds__(256) void k1(const float* __restrict__ inputs,
                                          const float* __restrict__ w,
                                          const float* __restrict__ aw1,
                                          const float* __restrict__ aw2,
                                          float* __restrict__ x,
                                          float* __restrict__ e1,
                                          float* __restrict__ e2,
                                          float* __restrict__ partial) {
    __shared__ float w_lds[F_IN * UNITS];
    __shared__ float in_lds[8 * F_IN];
    __shared__ float x_lds[8 * 65];
    __shared__ float aw_lds[2 * UNITS * HEADS];

    const int t = threadIdx.x;
    const int b = blockIdx.x;
    const int row0 = b * 8;

    {
        const float4* src = (const float4*)w;
        float4* dst = (float4*)w_lds;
        for (int idx = t; idx < F_IN * UNITS / 4; idx += 256) dst[idx] = src[idx];
    }
    {
        const float4* src = (const float4*)(inputs + (size_t)row0 * F_IN);
        float4* dst = (float4*)in_lds;
        dst[t] = src[t];
    }
    if (t < UNITS * HEADS) {
        aw_lds[t] = aw1[t];
        aw_lds[UNITS * HEADS + t] = aw2[t];
    }
    __syncthreads();

    const int u = t & 63;
    const int rg = t >> 6;
    float acc0 = 0.f, acc1 = 0.f;
    const float4* r0 = (const float4*)(in_lds + (rg * 2 + 0) * F_IN);
    const float4* r1 = (const float4*)(in_lds + (rg * 2 + 1) * F_IN);
#pragma unroll 8
    for (int c = 0; c < F_IN / 4; c++) {
        const int k4 = c * 4;
        const float w0 = w_lds[(k4 + 0) * UNITS + u];
        const float w1 = w_lds[(k4 + 1) * UNITS + u];
        const float w2 = w_lds[(k4 + 2) * UNITS + u];
        const float w3 = w_lds[(k4 + 3) * UNITS + u];
        float4 a;
        a = r0[c]; acc0 = fmaf(a.w, w3, fmaf(a.z, w2, fmaf(a.y, w1, fmaf(a.x, w0, acc0))));
        a = r1[c]; acc1 = fmaf(a.w, w3, fmaf(a.z, w2, fmaf(a.y, w1, fmaf(a.x, w0, acc1))));
    }
    x_lds[(rg * 2 + 0) * 65 + u] = acc0;
    x_lds[(rg * 2 + 1) * 65 + u] = acc1;
    x[(size_t)(row0 + rg * 2 + 0) * UNITS + u] = acc0;
    x[(size_t)(row0 + rg * 2 + 1) * UNITS + u] = acc1;
    __syncthreads();

    if (t < 64) {
        const int r = t >> 3;
        const int rem = t & 7;
        const int h = rem & 3;
        const bool first = rem < 4;
        const float* aw = aw_lds + (first ? 0 : UNITS * HEADS);
        float s = 0.f;
#pragma unroll 8
        for (int uu = 0; uu < UNITS; uu++)
            s += x_lds[r * 65 + uu] * aw[uu * HEADS + h];
        (first ? e1 : e2)[(size_t)(row0 + r) * HEADS + h] = s;
    }
    if (t < 64) {
        float s = 0.f;
#pragma unroll
        for (int r = 0; r < 8; r++) s += x_lds[r * 65 + t];
        partial[b * 64 + t] = s;
    }
}

__global__ __launch_bounds__(256) void k1b(const float* __restrict__ partial,
                                           float* __restrict__ S) {
    __shared__ float red[4][64];
    const int u = threadIdx.x & 63;
    const int q = threadIdx.x >> 6;
    float s = 0.f;
#pragma unroll 8
    for (int b = q; b < 512; b += 4) s += partial[b * 64 + u];
    red[q][u] = s;
    __syncthreads();
    if (threadIdx.x < 64) S[u] = red[0][u] + red[1][u] + red[2][u] + red[3][u];
}

__global__ __launch_bounds__(256) void k2(const float* __restrict__ adj,
                                          const float* __restrict__ x,
                                          const float* __restrict__ e1,
                                          const float* __restrict__ e2,
                                          const float* __restrict__ S,
                                          float* __restrict__ out) {
    __shared__ unsigned short nbr[N_NODES];
    __shared__ float4 wgt[K2_CHUNK];
    __shared__ float red[4][HEADS * UNITS];
    __shared__ float4 denred[4];
    __shared__ int cnt;

    const int i = blockIdx.x;
    const int t = threadIdx.x;
    const int lane = t & 63;
    const int wid = t >> 6;

    if (t == 0) cnt = 0;
    __syncthreads();

    const float4* arow = (const float4*)(adj + (size_t)i * N_NODES);
    const float4 v0 = arow[t];
    const float4 v1 = arow[t + 256];
    const float4 v2 = arow[t + 512];
    const float4 v3 = arow[t + 768];

    const unsigned long long b0  = __ballot(v0.x != 0.f);
    const unsigned long long b1  = __ballot(v0.y != 0.f);
    const unsigned long long b2  = __ballot(v0.z != 0.f);
    const unsigned long long b3  = __ballot(v0.w != 0.f);
    const unsigned long long b4  = __ballot(v1.x != 0.f);
    const unsigned long long b5  = __ballot(v1.y != 0.f);
    const unsigned long long b6  = __ballot(v1.z != 0.f);
    const unsigned long long b7  = __ballot(v1.w != 0.f);
    const unsigned long long b8  = __ballot(v2.x != 0.f);
    const unsigned long long b9  = __ballot(v2.y != 0.f);
    const unsigned long long b10 = __ballot(v2.z != 0.f);
    const unsigned long long b11 = __ballot(v2.w != 0.f);
    const unsigned long long b12 = __ballot(v3.x != 0.f);
    const unsigned long long b13 = __ballot(v3.y != 0.f);
    const unsigned long long b14 = __ballot(v3.z != 0.f);
    const unsigned long long b15 = __ballot(v3.w != 0.f);

    const int tot = __popcll(b0) + __popcll(b1) + __popcll(b2) + __popcll(b3)
                  + __popcll(b4) + __popcll(b5) + __popcll(b6) + __popcll(b7)
                  + __popcll(b8) + __popcll(b9) + __popcll(b10) + __popcll(b11)
                  + __popcll(b12) + __popcll(b13) + __popcll(b14) + __popcll(b15);

    int wbase = 0;
    if (lane == 0) wbase = atomicAdd(&cnt, tot);
    wbase = __shfl(wbase, 0);

    const unsigned long long lt = (1ull << lane) - 1ull;
    {
        int off = wbase;
        const int g0 = t * 4, g1 = (t + 256) * 4, g2 = (t + 512) * 4, g3 = (t + 768) * 4;
        if (v0.x != 0.f) nbr[off + __popcll(b0  & lt)] = (unsigned short)(g0 + 0); off += __popcll(b0);
        if (v0.y != 0.f) nbr[off + __popcll(b1  & lt)] = (unsigned short)(g0 + 1); off += __popcll(b1);
        if (v0.z != 0.f) nbr[off + __popcll(b2  & lt)] = (unsigned short)(g0 + 2); off += __popcll(b2);
        if (v0.w != 0.f) nbr[off + __popcll(b3  & lt)] = (unsigned short)(g0 + 3); off += __popcll(b3);
        if (v1.x != 0.f) nbr[off + __popcll(b4  & lt)] = (unsigned short)(g1 + 0); off += __popcll(b4);
        if (v1.y != 0.f) nbr[off + __popcll(b5  & lt)] = (unsigned short)(g1 + 1); off += __popcll(b5);
        if (v1.z != 0.f) nbr[off + __popcll(b6  & lt)] = (unsigned short)(g1 + 2); off += __popcll(b6);
        if (v1.w != 0.f) nbr[off + __popcll(b7  & lt)] = (unsigned short)(g1 + 3); off += __popcll(b7);
        if (v2.x != 0.f) nbr[off + __popcll(b8  & lt)] = (unsigned short)(g2 + 0); off += __popcll(b8);
        if (v2.y != 0.f) nbr[off + __popcll(b9  & lt)] = (unsigned short)(g2 + 1); off += __popcll(b9);
        if (v2.z != 0.f) nbr[off + __popcll(b10 & lt)] = (unsigned short)(g2 + 2); off += __popcll(b10);
        if (v2.w != 0.f) nbr[off + __popcll(b11 & lt)] = (unsigned short)(g2 + 3); off += __popcll(b11);
        if (v3.x != 0.f) nbr[off + __popcll(b12 & lt)] = (unsigned short)(g3 + 0); off += __popcll(b12);
        if (v3.y != 0.f) nbr[off + __popcll(b13 & lt)] = (unsigned short)(g3 + 1); off += __popcll(b13);
        if (v3.z != 0.f) nbr[off + __popcll(b14 & lt)] = (unsigned short)(g3 + 2); off += __popcll(b14);
        if (v3.w != 0.f) nbr[off + __popcll(b15 & lt)] = (unsigned short)(g3 + 3); off += __popcll(b15);
    }
    __syncthreads();

    const int n = cnt;
    const float4 e1v = *(const float4*)(e1 + (size_t)i * HEADS);

    float a0 = 0.f, a1 = 0.f, a2 = 0.f, a3 = 0.f;
    float4 dpart = make_float4(0.f, 0.f, 0.f, 0.f);

    for (int base = 0; base < n; base += K2_CHUNK) {
        const int m = min(n - base, K2_CHUNK);
        for (int k = t; k < m; k += 256) {
            const int j = nbr[base + k];
            const float4 e2v = *(const float4*)(e2 + (size_t)j * HEADS);
            float4 wv;
            wv.x = __expf(fmaxf(e1v.x + e2v.x, 0.f)) - 1.f;
            wv.y = __expf(fmaxf(e1v.y + e2v.y, 0.f)) - 1.f;
            wv.z = __expf(fmaxf(e1v.z + e2v.z, 0.f)) - 1.f;
            wv.w = __expf(fmaxf(e1v.w + e2v.w, 0.f)) - 1.f;
            wgt[k] = wv;
            dpart.x += wv.x; dpart.y += wv.y; dpart.z += wv.z; dpart.w += wv.w;
        }
        __syncthreads();
#pragma unroll 4
        for (int k = wid; k < m; k += 4) {
            const float4 p = wgt[k];
            const int j = nbr[base + k];
            const float xv = x[(j << 6) + lane];
            a0 = fmaf(p.x, xv, a0);
            a1 = fmaf(p.y, xv, a1);
            a2 = fmaf(p.z, xv, a2);
            a3 = fmaf(p.w, xv, a3);
        }
        __syncthreads();
    }

    dpart.x += __shfl_xor(dpart.x, 32); dpart.y += __shfl_xor(dpart.y, 32);
    dpart.z += __shfl_xor(dpart.z, 32); dpart.w += __shfl_xor(dpart.w, 32);
    dpart.x += __shfl_xor(dpart.x, 16); dpart.y += __shfl_xor(dpart.y, 16);
    dpart.z += __shfl_xor(dpart.z, 16); dpart.w += __shfl_xor(dpart.w, 16);
    dpart.x += __shfl_xor(dpart.x, 8);  dpart.y += __shfl_xor(dpart.y, 8);
    dpart.z += __shfl_xor(dpart.z, 8);  dpart.w += __shfl_xor(dpart.w, 8);
    dpart.x += __shfl_xor(dpart.x, 4);  dpart.y += __shfl_xor(dpart.y, 4);
    dpart.z += __shfl_xor(dpart.z, 4);  dpart.w += __shfl_xor(dpart.w, 4);
    dpart.x += __shfl_xor(dpart.x, 2);  dpart.y += __shfl_xor(dpart.y, 2);
    dpart.z += __shfl_xor(dpart.z, 2);  dpart.w += __shfl_xor(dpart.w, 2);
    dpart.x += __shfl_xor(dpart.x, 1);  dpart.y += __shfl_xor(dpart.y, 1);
    dpart.z += __shfl_xor(dpart.z, 1);  dpart.w += __shfl_xor(dpart.w, 1);

    red[wid][0 * 64 + lane] = a0;
    red[wid][1 * 64 + lane] = a1;
    red[wid][2 * 64 + lane] = a2;
    red[wid][3 * 64 + lane] = a3;
    if (lane == 0) denred[wid] = dpart;
    __syncthreads();

    const int h = wid;
    const int u = lane;
    const float accsum = red[0][h * 64 + u] + red[1][h * 64 + u]
                       + red[2][h * 64 + u] + red[3][h * 64 + u];
    const float* d0 = (const float*)&denred[0];
    const float* d1 = (const float*)&denred[1];
    const float* d2 = (const float*)&denred[2];
    const float* d3 = (const float*)&denred[3];
    const float den = d0[h] + d1[h] + d2[h] + d3[h];

    out[(size_t)i * (HEADS * UNITS) + t] =
        fmaxf((S[u] + accsum) / ((float)N_NODES + den), 0.f);
}

// ---------------------------------------------------------------------------
extern "C" void kernel_launch(void* const* d_in, const int* in_sizes, int n_in,
                              void* d_out, int out_size, void* d_ws, size_t ws_size,
                              hipStream_t stream) {
    const float* inputs = (const float*)d_in[0];
    const float* adj    = (const float*)d_in[1];
    const float* w      = (const float*)d_in[2];
    const float* aw1    = (const float*)d_in[3];
    const float* aw2    = (const float*)d_in[4];
    float* out = (float*)d_out;

    // workspace (floats): x[262144] | e2[16384] | S[64] | e1[16384] | partial[32768]
    float* ws = (float*)d_ws;
    float* x       = ws;
    float* e2      = ws + 262144;
    float* S       = ws + 262144 + 16384;
    float* e1      = ws + 262144 + 16384 + 64;
    float* partial = ws + 262144 + 2 * 16384 + 64;

    kzero<<<1, 64, 0, stream>>>(S);

    void* args[] = { (void*)&inputs, (void*)&adj, (void*)&w, (void*)&aw1, (void*)&aw2,
                     (void*)&x, (void*)&e2, (void*)&S, (void*)&out };
    hipError_t err = hipLaunchCooperativeKernel(kfused, dim3(GRID_F), dim3(256),
                                                args, 0u, stream);
    if (err != hipSuccess) {
        // fallback: proven round-2 3-kernel path
        k1<<<512, 256, 0, stream>>>(inputs, w, aw1, aw2, x, e1, e2, partial);
        k1b<<<1, 256, 0, stream>>>(partial, S);
        k2<<<N_NODES, 256, 0, stream>>>(adj, x, e1, e2, S, out);
    }
}

// Round 4
// 137.457 us; speedup vs baseline: 2.6668x; 2.6668x over previous
//
#include <hip/hip_runtime.h>

// Problem constants (from reference)
#define N_NODES 4096
#define F_IN    128
#define UNITS   64
#define HEADS   4
#define ROWS_PB 4                      // rows per k1 block
#define GRID1   (N_NODES / ROWS_PB)    // 1024 blocks = 4/CU resident (one generation)
#define NBR_CAP 128                    // per-row neighbor cap (mean 41, sd 6.4 -> 13.6 sigma)

// ---------------------------------------------------------------------------
// Kernel 1: fused  x = inputs@w,  e1/e2,  S partial (atomic),  adj scan +
// neighbor compaction.  1024 blocks x 256 threads, 4 rows per block.
//
// The key scheduling trick: each wave issues its row's 16 adj float4 loads
// into VGPRs, THEN runs the GEMM from LDS (no barrier between -> no
// vmcnt(0) drain), THEN consumes the loads with wave-local ballots.  The
// 64-MiB HBM scan streams underneath the GEMM's LDS/VALU work.  All 1024
// blocks are resident at once (LDS 36.2 KB, 4/CU), so each CU's full
// 256-KiB adj share is in flight in one volley.
//
// Compaction is wave-local (wave owns its whole row): running popcount
// prefix, ZERO atomics.  Compacted u16 lists + counts go to global for k2.
// ---------------------------------------------------------------------------
__global__ __launch_bounds__(256, 4) void k1(
        const float* __restrict__ inputs, const float* __restrict__ adj,
        const float* __restrict__ w, const float* __restrict__ aw1,
        const float* __restrict__ aw2, float* __restrict__ x,
        float* __restrict__ e1g, float* __restrict__ e2g,
        float* __restrict__ S, int* __restrict__ cnt_g,
        unsigned short* __restrict__ nbr_g)
{
    __shared__ float w_lds[F_IN * UNITS];               // 32 KB, natural [k][u]
    __shared__ float in_lds[ROWS_PB * F_IN];            // 2 KB
    __shared__ float x_lds[ROWS_PB * 65];               // 1.04 KB (pad 65)
    __shared__ unsigned short nbr_lds[ROWS_PB * NBR_CAP]; // 1 KB

    const int t    = threadIdx.x;
    const int lane = t & 63;
    const int wid  = t >> 6;
    const int row0 = blockIdx.x * ROWS_PB;
    const int r    = row0 + wid;            // this wave's row

    // ---- stage w (coalesced float4, no transpose) + 4 input rows ----
    {
        const float4* src = (const float4*)w;
        float4* dst = (float4*)w_lds;
        for (int idx = t; idx < F_IN * UNITS / 4; idx += 256) dst[idx] = src[idx];
    }
    if (t < ROWS_PB * F_IN / 4)
        ((float4*)in_lds)[t] = ((const float4*)(inputs + (size_t)row0 * F_IN))[t];
    __syncthreads();   // staging done (no adj loads outstanding yet)

    // ---- issue this wave's adj-row loads (16 float4/lane, 64 VGPR held) ----
    const float4* arow = (const float4*)(adj + (size_t)r * N_NODES);
    float4 av[16];
#pragma unroll
    for (int j = 0; j < 16; j++) av[j] = arow[lane + 64 * j];

    // ---- GEMM from LDS while the adj loads fly (no barrier in between!) ----
    // lane = column u; w read ds_read_b32 at bank=u%32 (2-way alias = free);
    // input row is wave-uniform -> broadcast b128.
    float acc = 0.f;
    const float4* ir = (const float4*)(in_lds + wid * F_IN);
#pragma unroll 8
    for (int c = 0; c < F_IN / 4; c++) {
        const float4 a = ir[c];
        const int k4 = c * 4;
        acc = fmaf(a.x, w_lds[(k4 + 0) * UNITS + lane],
              fmaf(a.y, w_lds[(k4 + 1) * UNITS + lane],
              fmaf(a.z, w_lds[(k4 + 2) * UNITS + lane],
              fmaf(a.w, w_lds[(k4 + 3) * UNITS + lane], acc))));
    }
    x_lds[wid * 65 + lane] = acc;
    x[(size_t)r * UNITS + lane] = acc;

    // ---- consume adj loads: wave-local ballot compaction (no atomics) ----
    int off = 0;                                   // uniform running count
    const unsigned long long lt = (1ull << lane) - 1ull;
#pragma unroll
    for (int j = 0; j < 16; j++) {
        const int gbase = 4 * (lane + 64 * j);     // column of av[j].x
        unsigned long long bm;
        bm = __ballot(av[j].x != 0.f);
        if (av[j].x != 0.f) { const int p = off + __popcll(bm & lt);
            if (p < NBR_CAP) nbr_lds[wid * NBR_CAP + p] = (unsigned short)(gbase + 0); }
        off += __popcll(bm);
        bm = __ballot(av[j].y != 0.f);
        if (av[j].y != 0.f) { const int p = off + __popcll(bm & lt);
            if (p < NBR_CAP) nbr_lds[wid * NBR_CAP + p] = (unsigned short)(gbase + 1); }
        off += __popcll(bm);
        bm = __ballot(av[j].z != 0.f);
        if (av[j].z != 0.f) { const int p = off + __popcll(bm & lt);
            if (p < NBR_CAP) nbr_lds[wid * NBR_CAP + p] = (unsigned short)(gbase + 2); }
        off += __popcll(bm);
        bm = __ballot(av[j].w != 0.f);
        if (av[j].w != 0.f) { const int p = off + __popcll(bm & lt);
            if (p < NBR_CAP) nbr_lds[wid * NBR_CAP + p] = (unsigned short)(gbase + 3); }
        off += __popcll(bm);
    }
    const int cntc = min(off, NBR_CAP);            // uniform across the wave
    if (lane == 0) cnt_g[r] = cntc;
    for (int idx = lane; idx < cntc; idx += 64)    // dump compacted list
        nbr_g[(size_t)r * NBR_CAP + idx] = nbr_lds[wid * NBR_CAP + idx];

    __syncthreads();   // x_lds complete (adj loads already consumed -> cheap drain)

    // ---- e1/e2: 4 rows x 4 heads x 2 = 32 tasks (aw1/aw2 are 1 KB, L2-hot) ----
    if (t < 32) {
        const int rr = t >> 3;
        const int rem = t & 7;
        const int h = rem & 3;
        const bool first = rem < 4;
        const float* aw = first ? aw1 : aw2;
        float s = 0.f;
#pragma unroll 8
        for (int uu = 0; uu < UNITS; uu++)
            s += x_lds[rr * 65 + uu] * aw[uu * HEADS + h];
        (first ? e1g : e2g)[(size_t)(row0 + rr) * HEADS + h] = s;
    }
    // ---- column-sum partial -> S (device-scope atomics; 64 lines x 1024 adds
    //      spread over the kernel's ~10 us: negligible contention) ----
    if (t < 64) {
        const float s = x_lds[0 * 65 + t] + x_lds[1 * 65 + t]
                      + x_lds[2 * 65 + t] + x_lds[3 * 65 + t];
        atomicAdd(&S[t], s);
    }
}

// ---------------------------------------------------------------------------
// Kernel 2: per row i — NO scan, NO compaction (precomputed by k1).
//   phase A: t<n threads load neighbor id + e2 row, compute all 4 head
//            weights (float4 -> LDS), stage ids in LDS
//   phase B: 4 waves split the neighbor list; x row loaded once per block
//            (L2/L3-hit, coalesced 256 B); lane carries 4 head accumulators;
//            den accumulated wave-uniformly (k-loop is wave-uniform)
//   cross-wave LDS reduction, coalesced out write.
// LDS ~6.6 KB -> thread-limited 8 blocks/CU.
// out[i, h*64+u] = relu((S[u]+acc_h)/(N+den_h)).
// ---------------------------------------------------------------------------
__global__ __launch_bounds__(256) void k2(
        const float* __restrict__ x, const float* __restrict__ e1g,
        const float* __restrict__ e2g, const float* __restrict__ S,
        const int* __restrict__ cnt_g, const unsigned short* __restrict__ nbr_g,
        float* __restrict__ out)
{
    __shared__ unsigned short nb[NBR_CAP];    // 256 B
    __shared__ float4 wgt[NBR_CAP];           // 2 KB
    __shared__ float red[4][HEADS * UNITS];   // 4 KB
    __shared__ float4 denred[4];

    const int i = blockIdx.x;
    const int t = threadIdx.x;
    const int lane = t & 63;
    const int wid = t >> 6;

    const int n = min(cnt_g[i], NBR_CAP);     // block-uniform -> scalar
    const float4 e1v = *(const float4*)(e1g + (size_t)i * HEADS);

    // phase A (n <= 128 < 256 always)
    if (t < n) {
        const int j = nbr_g[(size_t)i * NBR_CAP + t];
        nb[t] = (unsigned short)j;
        const float4 e2v = *(const float4*)(e2g + (size_t)j * HEADS);
        float4 wv;
        wv.x = __expf(fmaxf(e1v.x + e2v.x, 0.f)) - 1.f;
        wv.y = __expf(fmaxf(e1v.y + e2v.y, 0.f)) - 1.f;
        wv.z = __expf(fmaxf(e1v.z + e2v.z, 0.f)) - 1.f;
        wv.w = __expf(fmaxf(e1v.w + e2v.w, 0.f)) - 1.f;
        wgt[t] = wv;
    }
    __syncthreads();

    // phase B: waves split the neighbor list
    float a0 = 0.f, a1 = 0.f, a2 = 0.f, a3 = 0.f;
    float dx = 0.f, dy = 0.f, dz = 0.f, dw = 0.f;
    for (int k = wid; k < n; k += 4) {
        const float4 p = wgt[k];              // broadcast ds_read_b128
        const int j = nb[k];                  // uniform LDS read
        const float xv = x[(j << 6) + lane];  // coalesced 256 B, L2/L3-hit
        a0 = fmaf(p.x, xv, a0);
        a1 = fmaf(p.y, xv, a1);
        a2 = fmaf(p.z, xv, a2);
        a3 = fmaf(p.w, xv, a3);
        dx += p.x; dy += p.y; dz += p.z; dw += p.w;   // wave-uniform
    }
    red[wid][0 * 64 + lane] = a0;
    red[wid][1 * 64 + lane] = a1;
    red[wid][2 * 64 + lane] = a2;
    red[wid][3 * 64 + lane] = a3;
    if (lane == 0) denred[wid] = make_float4(dx, dy, dz, dw);
    __syncthreads();

    // thread t = (h=t>>6, u=t&63): red[w][h*64+u] summed over waves w
    const float accsum = red[0][t] + red[1][t] + red[2][t] + red[3][t];
    const float den = ((const float*)&denred[0])[wid]
                    + ((const float*)&denred[1])[wid]
                    + ((const float*)&denred[2])[wid]
                    + ((const float*)&denred[3])[wid];
    out[(size_t)i * (HEADS * UNITS) + t] =
        fmaxf((S[lane] + accsum) / ((float)N_NODES + den), 0.f);
}

// ---------------------------------------------------------------------------
extern "C" void kernel_launch(void* const* d_in, const int* in_sizes, int n_in,
                              void* d_out, int out_size, void* d_ws, size_t ws_size,
                              hipStream_t stream) {
    const float* inputs = (const float*)d_in[0];
    const float* adj    = (const float*)d_in[1];
    const float* w      = (const float*)d_in[2];
    const float* aw1    = (const float*)d_in[3];
    const float* aw2    = (const float*)d_in[4];
    float* out = (float*)d_out;

    // workspace (floats):
    //   x[262144] | e1[16384] | e2[16384] | S[64] | cnt[4096 ints]
    //   | nbr[4096*128 u16 = 262144 float-slots... (131072 floats)]
    float* ws = (float*)d_ws;
    float* x   = ws;
    float* e1  = ws + 262144;
    float* e2  = ws + 262144 + 16384;
    float* S   = ws + 262144 + 2 * 16384;
    int*   cnt = (int*)(ws + 262144 + 2 * 16384 + 64);
    unsigned short* nbr = (unsigned short*)(ws + 262144 + 2 * 16384 + 64 + 4096);

    hipMemsetAsync(S, 0, UNITS * sizeof(float), stream);  // graph-capture-safe
    k1<<<GRID1, 256, 0, stream>>>(inputs, adj, w, aw1, aw2, x, e1, e2, S, cnt, nbr);
    k2<<<N_NODES, 256, 0, stream>>>(x, e1, e2, S, cnt, nbr, out);
}

// Round 5
// 134.505 us; speedup vs baseline: 2.7254x; 1.0220x over previous
//
#include <hip/hip_runtime.h>

// Problem constants (from reference)
#define N_NODES 4096
#define F_IN    128
#define UNITS   64
#define HEADS   4
#define ROWS_PB 4                       // rows per GEMM block
#define GRID_GEMM (N_NODES / ROWS_PB)   // 1024 GEMM blocks
#define GRID_A  (GRID_GEMM + N_NODES)   // 5120 total: 1 GEMM per 4 scan, interleaved
#define NBR_CAP 128                     // per-row neighbor cap (mean 41, sd 6.4)

// ---------------------------------------------------------------------------
// Kernel A: role-split blocks, NO grid sync (roles are independent).
//   bid % 5 == 0  -> GEMM role (1024 blocks): stage w, x = inputs@w for 4 rows,
//                    e1/e2, S column-sum via device atomics.
//   else          -> scan role (4096 blocks): round-2's proven per-row adj
//                    scan (64 B/thread float4, ballot compaction, 1 LDS atomic
//                    per wave), dump compacted u16 list + count to global.
// Interleaving in blockIdx order co-schedules ~1:4 GEMM:scan per CU, so the
// GEMM's VALU/LDS work hides under the scan's memory streaming (adj is ~half
// L3-resident per round-4 FETCH_SIZE, rest HBM).
// LDS = max(GEMM 35.3 KB, scan 0.3 KB) = 35.3 KB -> 4 blocks/CU.
// ---------------------------------------------------------------------------
struct GemmS { float w[F_IN * UNITS]; float in[ROWS_PB * F_IN]; float xl[ROWS_PB * 65]; };
struct ScanS { unsigned short nbr[NBR_CAP]; };

__global__ __launch_bounds__(256) void kA(
        const float* __restrict__ inputs, const float* __restrict__ adj,
        const float* __restrict__ w, const float* __restrict__ aw1,
        const float* __restrict__ aw2, float* __restrict__ x,
        float* __restrict__ e1g, float* __restrict__ e2g,
        float* __restrict__ S, int* __restrict__ cnt_g,
        unsigned short* __restrict__ nbr_g)
{
    __shared__ union { GemmS g; ScanS s; } u;
    __shared__ int cnt;

    const int bid  = blockIdx.x;
    const int t    = threadIdx.x;
    const int lane = t & 63;
    const int wid  = t >> 6;

    if (bid % 5 == 0) {
        // ================= GEMM role =================
        const int row0 = (bid / 5) * ROWS_PB;

        {   // stage w (coalesced float4, natural [k][u] layout)
            const float4* src = (const float4*)w;
            float4* dst = (float4*)u.g.w;
            for (int idx = t; idx < F_IN * UNITS / 4; idx += 256) dst[idx] = src[idx];
        }
        if (t < ROWS_PB * F_IN / 4)
            ((float4*)u.g.in)[t] = ((const float4*)(inputs + (size_t)row0 * F_IN))[t];
        __syncthreads();

        // wave wid -> row row0+wid, lane -> column u.
        // w reads: ds_read_b32 at bank=u%32 (2-way alias = free);
        // input row wave-uniform -> broadcast b128.
        float acc = 0.f;
        const float4* ir = (const float4*)(u.g.in + wid * F_IN);
#pragma unroll 8
        for (int c = 0; c < F_IN / 4; c++) {
            const float4 a = ir[c];
            const int k4 = c * 4;
            acc = fmaf(a.x, u.g.w[(k4 + 0) * UNITS + lane],
                  fmaf(a.y, u.g.w[(k4 + 1) * UNITS + lane],
                  fmaf(a.z, u.g.w[(k4 + 2) * UNITS + lane],
                  fmaf(a.w, u.g.w[(k4 + 3) * UNITS + lane], acc))));
        }
        u.g.xl[wid * 65 + lane] = acc;
        x[(size_t)(row0 + wid) * UNITS + lane] = acc;
        __syncthreads();

        // e1/e2: 4 rows x 4 heads x 2 = 32 tasks (aw1/aw2 1 KB each, cache-hot)
        if (t < 32) {
            const int rr = t >> 3;
            const int rem = t & 7;
            const int h = rem & 3;
            const bool first = rem < 4;
            const float* aw = first ? aw1 : aw2;
            float s = 0.f;
#pragma unroll 8
            for (int uu = 0; uu < UNITS; uu++)
                s += u.g.xl[rr * 65 + uu] * aw[uu * HEADS + h];
            (first ? e1g : e2g)[(size_t)(row0 + rr) * HEADS + h] = s;
        }
        // S column-sum partial (device-scope atomics; 64 lines x 1024 adds
        // spread across the kernel: negligible contention)
        if (t < 64) {
            const float s = u.g.xl[0 * 65 + t] + u.g.xl[1 * 65 + t]
                          + u.g.xl[2 * 65 + t] + u.g.xl[3 * 65 + t];
            atomicAdd(&S[t], s);
        }
    } else {
        // ================= scan role =================
        const int i = bid - bid / 5 - 1;    // scan row index 0..4095

        if (t == 0) cnt = 0;
        __syncthreads();

        // 64 B/thread, 16 KiB/block contiguous row — proven streaming shape
        const float4* arow = (const float4*)(adj + (size_t)i * N_NODES);
        const float4 v0 = arow[t];
        const float4 v1 = arow[t + 256];
        const float4 v2 = arow[t + 512];
        const float4 v3 = arow[t + 768];

        const unsigned long long b0  = __ballot(v0.x != 0.f);
        const unsigned long long b1  = __ballot(v0.y != 0.f);
        const unsigned long long b2  = __ballot(v0.z != 0.f);
        const unsigned long long b3  = __ballot(v0.w != 0.f);
        const unsigned long long b4  = __ballot(v1.x != 0.f);
        const unsigned long long b5  = __ballot(v1.y != 0.f);
        const unsigned long long b6  = __ballot(v1.z != 0.f);
        const unsigned long long b7  = __ballot(v1.w != 0.f);
        const unsigned long long b8  = __ballot(v2.x != 0.f);
        const unsigned long long b9  = __ballot(v2.y != 0.f);
        const unsigned long long b10 = __ballot(v2.z != 0.f);
        const unsigned long long b11 = __ballot(v2.w != 0.f);
        const unsigned long long b12 = __ballot(v3.x != 0.f);
        const unsigned long long b13 = __ballot(v3.y != 0.f);
        const unsigned long long b14 = __ballot(v3.z != 0.f);
        const unsigned long long b15 = __ballot(v3.w != 0.f);

        const int tot = __popcll(b0) + __popcll(b1) + __popcll(b2) + __popcll(b3)
                      + __popcll(b4) + __popcll(b5) + __popcll(b6) + __popcll(b7)
                      + __popcll(b8) + __popcll(b9) + __popcll(b10) + __popcll(b11)
                      + __popcll(b12) + __popcll(b13) + __popcll(b14) + __popcll(b15);

        int wbase = 0;
        if (lane == 0) wbase = atomicAdd(&cnt, tot);   // ONE LDS atomic per wave
        wbase = __shfl(wbase, 0);

        const unsigned long long lt = (1ull << lane) - 1ull;
        int off = wbase;
        const int g0 = t * 4, g1 = (t + 256) * 4, g2 = (t + 512) * 4, g3 = (t + 768) * 4;
#define EMIT(val, bm, gidx) \
        do { if ((val) != 0.f) { const int p_ = off + __popcll((bm) & lt); \
             if (p_ < NBR_CAP) u.s.nbr[p_] = (unsigned short)(gidx); } \
             off += __popcll(bm); } while (0)
        EMIT(v0.x, b0,  g0 + 0); EMIT(v0.y, b1,  g0 + 1);
        EMIT(v0.z, b2,  g0 + 2); EMIT(v0.w, b3,  g0 + 3);
        EMIT(v1.x, b4,  g1 + 0); EMIT(v1.y, b5,  g1 + 1);
        EMIT(v1.z, b6,  g1 + 2); EMIT(v1.w, b7,  g1 + 3);
        EMIT(v2.x, b8,  g2 + 0); EMIT(v2.y, b9,  g2 + 1);
        EMIT(v2.z, b10, g2 + 2); EMIT(v2.w, b11, g2 + 3);
        EMIT(v3.x, b12, g3 + 0); EMIT(v3.y, b13, g3 + 1);
        EMIT(v3.z, b14, g3 + 2); EMIT(v3.w, b15, g3 + 3);
#undef EMIT
        __syncthreads();

        const int n = min(cnt, NBR_CAP);
        if (t < n) nbr_g[(size_t)i * NBR_CAP + t] = u.s.nbr[t];   // n <= 128 < 256
        if (t == 0) cnt_g[i] = n;
    }
}

// ---------------------------------------------------------------------------
// Kernel B: per row i — no scan, no compaction (precomputed by kA).
//   phase A: t<n threads load neighbor id + e2 row, compute all 4 head
//            weights (float4 -> LDS), stage ids in LDS
//   phase B: 4 waves split the neighbor list; x row loaded once per block
//            (L2/L3-hit, coalesced 256 B); lane carries 4 head accumulators;
//            den accumulated wave-uniformly
//   cross-wave LDS reduction, coalesced out write.
// out[i, h*64+u] = relu((S[u]+acc_h)/(N+den_h)).
// ---------------------------------------------------------------------------
__global__ __launch_bounds__(256) void kB(
        const float* __restrict__ x, const float* __restrict__ e1g,
        const float* __restrict__ e2g, const float* __restrict__ S,
        const int* __restrict__ cnt_g, const unsigned short* __restrict__ nbr_g,
        float* __restrict__ out)
{
    __shared__ unsigned short nb[NBR_CAP];    // 256 B
    __shared__ float4 wgt[NBR_CAP];           // 2 KB
    __shared__ float red[4][HEADS * UNITS];   // 4 KB
    __shared__ float4 denred[4];

    const int i = blockIdx.x;
    const int t = threadIdx.x;
    const int lane = t & 63;
    const int wid = t >> 6;

    const int n = min(cnt_g[i], NBR_CAP);     // block-uniform -> scalar
    const float4 e1v = *(const float4*)(e1g + (size_t)i * HEADS);

    // phase A (n <= 128 < 256 always)
    if (t < n) {
        const int j = nbr_g[(size_t)i * NBR_CAP + t];
        nb[t] = (unsigned short)j;
        const float4 e2v = *(const float4*)(e2g + (size_t)j * HEADS);
        float4 wv;
        wv.x = __expf(fmaxf(e1v.x + e2v.x, 0.f)) - 1.f;
        wv.y = __expf(fmaxf(e1v.y + e2v.y, 0.f)) - 1.f;
        wv.z = __expf(fmaxf(e1v.z + e2v.z, 0.f)) - 1.f;
        wv.w = __expf(fmaxf(e1v.w + e2v.w, 0.f)) - 1.f;
        wgt[t] = wv;
    }
    __syncthreads();

    // phase B: waves split the neighbor list
    float a0 = 0.f, a1 = 0.f, a2 = 0.f, a3 = 0.f;
    float dx = 0.f, dy = 0.f, dz = 0.f, dw = 0.f;
    for (int k = wid; k < n; k += 4) {
        const float4 p = wgt[k];              // broadcast ds_read_b128
        const int j = nb[k];                  // uniform LDS read
        const float xv = x[(j << 6) + lane];  // coalesced 256 B, L2/L3-hit
        a0 = fmaf(p.x, xv, a0);
        a1 = fmaf(p.y, xv, a1);
        a2 = fmaf(p.z, xv, a2);
        a3 = fmaf(p.w, xv, a3);
        dx += p.x; dy += p.y; dz += p.z; dw += p.w;   // wave-uniform
    }
    red[wid][0 * 64 + lane] = a0;
    red[wid][1 * 64 + lane] = a1;
    red[wid][2 * 64 + lane] = a2;
    red[wid][3 * 64 + lane] = a3;
    if (lane == 0) denred[wid] = make_float4(dx, dy, dz, dw);
    __syncthreads();

    // thread t = (h=t>>6, u=t&63): red[w][h*64+u] summed over waves w
    const float accsum = red[0][t] + red[1][t] + red[2][t] + red[3][t];
    const float den = ((const float*)&denred[0])[wid]
                    + ((const float*)&denred[1])[wid]
                    + ((const float*)&denred[2])[wid]
                    + ((const float*)&denred[3])[wid];
    out[(size_t)i * (HEADS * UNITS) + t] =
        fmaxf((S[lane] + accsum) / ((float)N_NODES + den), 0.f);
}

// ---------------------------------------------------------------------------
extern "C" void kernel_launch(void* const* d_in, const int* in_sizes, int n_in,
                              void* d_out, int out_size, void* d_ws, size_t ws_size,
                              hipStream_t stream) {
    const float* inputs = (const float*)d_in[0];
    const float* adj    = (const float*)d_in[1];
    const float* w      = (const float*)d_in[2];
    const float* aw1    = (const float*)d_in[3];
    const float* aw2    = (const float*)d_in[4];
    float* out = (float*)d_out;

    // workspace (floats):
    //   x[262144] | e1[16384] | e2[16384] | S[64] | cnt[4096 ints]
    //   | nbr[4096*128 u16 = 131072 float-slots]
    float* ws = (float*)d_ws;
    float* x   = ws;
    float* e1  = ws + 262144;
    float* e2  = ws + 262144 + 16384;
    float* S   = ws + 262144 + 2 * 16384;
    int*   cnt = (int*)(ws + 262144 + 2 * 16384 + 64);
    unsigned short* nbr = (unsigned short*)(ws + 262144 + 2 * 16384 + 64 + 4096);

    hipMemsetAsync(S, 0, UNITS * sizeof(float), stream);  // graph-capture-safe
    kA<<<GRID_A, 256, 0, stream>>>(inputs, adj, w, aw1, aw2, x, e1, e2, S, cnt, nbr);
    kB<<<N_NODES, 256, 0, stream>>>(x, e1, e2, S, cnt, nbr, out);
}

// Round 6
// 125.033 us; speedup vs baseline: 2.9318x; 1.0758x over previous
//
#include <hip/hip_runtime.h>

// Problem constants (from reference)
#define N_NODES 4096
#define F_IN    128
#define UNITS   64
#define HEADS   4
#define K2_CHUNK 256   // neighbor chunk (typical n ~41, max ~75 -> single chunk)

// ---------------------------------------------------------------------------
// Kernel 1: x = inputs @ w  [N,64], e1 = x @ attn_w1 [N,4], e2 = x @ attn_w2,
//           plus S column sums via device-scope atomics (k1b eliminated).
// 512 blocks x 256 threads; each block handles 8 rows -> 2 blocks/CU.
// w staged in NATURAL [k][u] layout: column reads are ds_read_b32 at
// bank = u mod 32 -> 2-way aliasing = free.
// (Proven round-2 structure; only the partial-sum sink changed.)
// ---------------------------------------------------------------------------
__global__ __launch_bounds__(256) void k1(const float* __restrict__ inputs,
                                          const float* __restrict__ w,
                                          const float* __restrict__ aw1,
                                          const float* __restrict__ aw2,
                                          float* __restrict__ x,
                                          float* __restrict__ e1,
                                          float* __restrict__ e2,
                                          float* __restrict__ S) {
    __shared__ float w_lds[F_IN * UNITS];       // 32 KB, natural [k][u]
    __shared__ float in_lds[8 * F_IN];          // 4 KB
    __shared__ float x_lds[8 * 65];             // padded stride 65
    __shared__ float aw_lds[2 * UNITS * HEADS]; // aw1 then aw2 (2 KB)

    const int t = threadIdx.x;
    const int b = blockIdx.x;
    const int row0 = b * 8;

    // stage w (coalesced float4 copy, no transpose)
    {
        const float4* src = (const float4*)w;
        float4* dst = (float4*)w_lds;
        for (int idx = t; idx < F_IN * UNITS / 4; idx += 256) dst[idx] = src[idx];
    }
    // stage 8 input rows (coalesced float4: 256 float4s, one per thread)
    {
        const float4* src = (const float4*)(inputs + (size_t)row0 * F_IN);
        float4* dst = (float4*)in_lds;
        dst[t] = src[t];
    }
    // stage attention vectors
    if (t < UNITS * HEADS) {
        aw_lds[t] = aw1[t];
        aw_lds[UNITS * HEADS + t] = aw2[t];
    }
    __syncthreads();

    // thread u = t&63 handles column u for rows rg*2, rg*2+1
    const int u = t & 63;
    const int rg = t >> 6;
    float acc0 = 0.f, acc1 = 0.f;
    const float4* r0 = (const float4*)(in_lds + (rg * 2 + 0) * F_IN);
    const float4* r1 = (const float4*)(in_lds + (rg * 2 + 1) * F_IN);
#pragma unroll 8
    for (int c = 0; c < F_IN / 4; c++) {
        const int k4 = c * 4;
        const float w0 = w_lds[(k4 + 0) * UNITS + u];   // 2-way bank alias: free
        const float w1 = w_lds[(k4 + 1) * UNITS + u];
        const float w2 = w_lds[(k4 + 2) * UNITS + u];
        const float w3 = w_lds[(k4 + 3) * UNITS + u];
        float4 a;
        a = r0[c]; acc0 = fmaf(a.w, w3, fmaf(a.z, w2, fmaf(a.y, w1, fmaf(a.x, w0, acc0))));
        a = r1[c]; acc1 = fmaf(a.w, w3, fmaf(a.z, w2, fmaf(a.y, w1, fmaf(a.x, w0, acc1))));
    }
    x_lds[(rg * 2 + 0) * 65 + u] = acc0;
    x_lds[(rg * 2 + 1) * 65 + u] = acc1;
    x[(size_t)(row0 + rg * 2 + 0) * UNITS + u] = acc0;
    x[(size_t)(row0 + rg * 2 + 1) * UNITS + u] = acc1;
    __syncthreads();

    // e1/e2: 8 rows x 4 heads x 2 matrices = 64 tasks
    if (t < 64) {
        const int r = t >> 3;
        const int rem = t & 7;
        const int h = rem & 3;
        const bool first = rem < 4;
        const float* aw = aw_lds + (first ? 0 : UNITS * HEADS);
        float s = 0.f;
#pragma unroll 8
        for (int uu = 0; uu < UNITS; uu++)
            s += x_lds[r * 65 + uu] * aw[uu * HEADS + h];
        (first ? e1 : e2)[(size_t)(row0 + r) * HEADS + h] = s;
    }

    // column sums of x over this block's 8 rows -> S (device-scope atomics;
    // 64 lines x 512 adds spread across the kernel: negligible contention)
    if (t < 64) {
        float s = 0.f;
#pragma unroll
        for (int r = 0; r < 8; r++) s += x_lds[r * 65 + t];
        atomicAdd(&S[t], s);
    }
}

// ---------------------------------------------------------------------------
// Kernel 2 (round-2 proven, verbatim): per row i.
//   - ballot-based neighbor compaction (1 LDS atomic per WAVE)
//   - phase A: all 4 head-weights per neighbor computed ONCE (float4 -> LDS),
//     per-thread den partials accumulated here (out of the hot loop)
//   - phase B: the 4 waves split the NEIGHBOR LIST (k = wave, wave+4, ...).
//     Each x row is loaded once per block, each lane carries 4 head
//     accumulators. Inner loop per neighbor: 1 broadcast ds_read_b128 +
//     1 uniform nbr read + 1 coalesced b32 + 4 FMA.
//   - final 4-way cross-wave LDS reduction recombines.
// LDS ~16.3 KB; out[i, h*64+u] = relu((S[u]+acc_h)/(N+den_h)).
// ---------------------------------------------------------------------------
__global__ __launch_bounds__(256) void k2(const float* __restrict__ adj,
                                          const float* __restrict__ x,
                                          const float* __restrict__ e1,
                                          const float* __restrict__ e2,
                                          const float* __restrict__ S,
                                          float* __restrict__ out) {
    __shared__ unsigned short nbr[N_NODES];   // 8 KB — worst case all neighbors
    __shared__ float4 wgt[K2_CHUNK];          // 4 KB — per-neighbor head weights
    __shared__ float red[4][HEADS * UNITS];   // 4 KB — per-wave partial sums
    __shared__ float4 denred[4];              // per-wave den partials
    __shared__ int cnt;

    const int i = blockIdx.x;
    const int t = threadIdx.x;
    const int lane = t & 63;
    const int wid = t >> 6;

    if (t == 0) cnt = 0;
    __syncthreads();

    // scan adjacency row: issue all 4 float4 loads up front (latency overlap)
    const float4* arow = (const float4*)(adj + (size_t)i * N_NODES);
    const float4 v0 = arow[t];
    const float4 v1 = arow[t + 256];
    const float4 v2 = arow[t + 512];
    const float4 v3 = arow[t + 768];

    // ballots are wave-uniform -> live in SGPR pairs
    const unsigned long long b0  = __ballot(v0.x != 0.f);
    const unsigned long long b1  = __ballot(v0.y != 0.f);
    const unsigned long long b2  = __ballot(v0.z != 0.f);
    const unsigned long long b3  = __ballot(v0.w != 0.f);
    const unsigned long long b4  = __ballot(v1.x != 0.f);
    const unsigned long long b5  = __ballot(v1.y != 0.f);
    const unsigned long long b6  = __ballot(v1.z != 0.f);
    const unsigned long long b7  = __ballot(v1.w != 0.f);
    const unsigned long long b8  = __ballot(v2.x != 0.f);
    const unsigned long long b9  = __ballot(v2.y != 0.f);
    const unsigned long long b10 = __ballot(v2.z != 0.f);
    const unsigned long long b11 = __ballot(v2.w != 0.f);
    const unsigned long long b12 = __ballot(v3.x != 0.f);
    const unsigned long long b13 = __ballot(v3.y != 0.f);
    const unsigned long long b14 = __ballot(v3.z != 0.f);
    const unsigned long long b15 = __ballot(v3.w != 0.f);

    const int tot = __popcll(b0) + __popcll(b1) + __popcll(b2) + __popcll(b3)
                  + __popcll(b4) + __popcll(b5) + __popcll(b6) + __popcll(b7)
                  + __popcll(b8) + __popcll(b9) + __popcll(b10) + __popcll(b11)
                  + __popcll(b12) + __popcll(b13) + __popcll(b14) + __popcll(b15);

    int wbase = 0;
    if (lane == 0) wbase = atomicAdd(&cnt, tot);   // ONE atomic per wave
    wbase = __shfl(wbase, 0);

    const unsigned long long lt = (1ull << lane) - 1ull;
    {
        int off = wbase;
        const int g0 = t * 4, g1 = (t + 256) * 4, g2 = (t + 512) * 4, g3 = (t + 768) * 4;
        if (v0.x != 0.f) nbr[off + __popcll(b0  & lt)] = (unsigned short)(g0 + 0); off += __popcll(b0);
        if (v0.y != 0.f) nbr[off + __popcll(b1  & lt)] = (unsigned short)(g0 + 1); off += __popcll(b1);
        if (v0.z != 0.f) nbr[off + __popcll(b2  & lt)] = (unsigned short)(g0 + 2); off += __popcll(b2);
        if (v0.w != 0.f) nbr[off + __popcll(b3  & lt)] = (unsigned short)(g0 + 3); off += __popcll(b3);
        if (v1.x != 0.f) nbr[off + __popcll(b4  & lt)] = (unsigned short)(g1 + 0); off += __popcll(b4);
        if (v1.y != 0.f) nbr[off + __popcll(b5  & lt)] = (unsigned short)(g1 + 1); off += __popcll(b5);
        if (v1.z != 0.f) nbr[off + __popcll(b6  & lt)] = (unsigned short)(g1 + 2); off += __popcll(b6);
        if (v1.w != 0.f) nbr[off + __popcll(b7  & lt)] = (unsigned short)(g1 + 3); off += __popcll(b7);
        if (v2.x != 0.f) nbr[off + __popcll(b8  & lt)] = (unsigned short)(g2 + 0); off += __popcll(b8);
        if (v2.y != 0.f) nbr[off + __popcll(b9  & lt)] = (unsigned short)(g2 + 1); off += __popcll(b9);
        if (v2.z != 0.f) nbr[off + __popcll(b10 & lt)] = (unsigned short)(g2 + 2); off += __popcll(b10);
        if (v2.w != 0.f) nbr[off + __popcll(b11 & lt)] = (unsigned short)(g2 + 3); off += __popcll(b11);
        if (v3.x != 0.f) nbr[off + __popcll(b12 & lt)] = (unsigned short)(g3 + 0); off += __popcll(b12);
        if (v3.y != 0.f) nbr[off + __popcll(b13 & lt)] = (unsigned short)(g3 + 1); off += __popcll(b13);
        if (v3.z != 0.f) nbr[off + __popcll(b14 & lt)] = (unsigned short)(g3 + 2); off += __popcll(b14);
        if (v3.w != 0.f) nbr[off + __popcll(b15 & lt)] = (unsigned short)(g3 + 3); off += __popcll(b15);
    }
    __syncthreads();

    const int n = cnt;
    const float4 e1v = *(const float4*)(e1 + (size_t)i * HEADS);

    float a0 = 0.f, a1 = 0.f, a2 = 0.f, a3 = 0.f;   // per-head accumulators
    float4 dpart = make_float4(0.f, 0.f, 0.f, 0.f); // per-thread den partials

    for (int base = 0; base < n; base += K2_CHUNK) {
        const int m = min(n - base, K2_CHUNK);

        // phase A: weights for this chunk, one thread per neighbor
        for (int k = t; k < m; k += 256) {
            const int j = nbr[base + k];
            const float4 e2v = *(const float4*)(e2 + (size_t)j * HEADS);
            float4 wv;
            wv.x = __expf(fmaxf(e1v.x + e2v.x, 0.f)) - 1.f;
            wv.y = __expf(fmaxf(e1v.y + e2v.y, 0.f)) - 1.f;
            wv.z = __expf(fmaxf(e1v.z + e2v.z, 0.f)) - 1.f;
            wv.w = __expf(fmaxf(e1v.w + e2v.w, 0.f)) - 1.f;
            wgt[k] = wv;
            dpart.x += wv.x; dpart.y += wv.y; dpart.z += wv.z; dpart.w += wv.w;
        }
        __syncthreads();

        // phase B: waves split the neighbor list; x row loaded once per block
#pragma unroll 4
        for (int k = wid; k < m; k += 4) {
            const float4 p = wgt[k];                    // broadcast ds_read_b128
            const int j = nbr[base + k];                // uniform LDS read
            const float xv = x[(j << 6) + lane];        // coalesced 256 B, L1/L2-hit
            a0 = fmaf(p.x, xv, a0);
            a1 = fmaf(p.y, xv, a1);
            a2 = fmaf(p.z, xv, a2);
            a3 = fmaf(p.w, xv, a3);
        }
        __syncthreads();   // protect wgt before next chunk overwrites
    }

    // wave-reduce den partials (once, outside the hot loop)
    dpart.x += __shfl_xor(dpart.x, 32); dpart.y += __shfl_xor(dpart.y, 32);
    dpart.z += __shfl_xor(dpart.z, 32); dpart.w += __shfl_xor(dpart.w, 32);
    dpart.x += __shfl_xor(dpart.x, 16); dpart.y += __shfl_xor(dpart.y, 16);
    dpart.z += __shfl_xor(dpart.z, 16); dpart.w += __shfl_xor(dpart.w, 16);
    dpart.x += __shfl_xor(dpart.x, 8);  dpart.y += __shfl_xor(dpart.y, 8);
    dpart.z += __shfl_xor(dpart.z, 8);  dpart.w += __shfl_xor(dpart.w, 8);
    dpart.x += __shfl_xor(dpart.x, 4);  dpart.y += __shfl_xor(dpart.y, 4);
    dpart.z += __shfl_xor(dpart.z, 4);  dpart.w += __shfl_xor(dpart.w, 4);
    dpart.x += __shfl_xor(dpart.x, 2);  dpart.y += __shfl_xor(dpart.y, 2);
    dpart.z += __shfl_xor(dpart.z, 2);  dpart.w += __shfl_xor(dpart.w, 2);
    dpart.x += __shfl_xor(dpart.x, 1);  dpart.y += __shfl_xor(dpart.y, 1);
    dpart.z += __shfl_xor(dpart.z, 1);  dpart.w += __shfl_xor(dpart.w, 1);

    // per-wave partials -> LDS
    red[wid][0 * 64 + lane] = a0;
    red[wid][1 * 64 + lane] = a1;
    red[wid][2 * 64 + lane] = a2;
    red[wid][3 * 64 + lane] = a3;
    if (lane == 0) denred[wid] = dpart;
    __syncthreads();

    // thread t = (h, u): recombine 4 wave-partials
    const int h = wid;         // output head = wave id
    const int u = lane;
    const float accsum = red[0][h * 64 + u] + red[1][h * 64 + u]
                       + red[2][h * 64 + u] + red[3][h * 64 + u];
    const float* d0 = (const float*)&denred[0];
    const float* d1 = (const float*)&denred[1];
    const float* d2 = (const float*)&denred[2];
    const float* d3 = (const float*)&denred[3];
    const float den = d0[h] + d1[h] + d2[h] + d3[h];

    const float numer = S[u] + accsum;
    const float denom = (float)N_NODES + den;
    out[(size_t)i * (HEADS * UNITS) + t] = fmaxf(numer / denom, 0.f);
}

// ---------------------------------------------------------------------------
extern "C" void kernel_launch(void* const* d_in, const int* in_sizes, int n_in,
                              void* d_out, int out_size, void* d_ws, size_t ws_size,
                              hipStream_t stream) {
    const float* inputs = (const float*)d_in[0];
    const float* adj    = (const float*)d_in[1];
    const float* w      = (const float*)d_in[2];
    const float* aw1    = (const float*)d_in[3];
    const float* aw2    = (const float*)d_in[4];
    float* out = (float*)d_out;

    // workspace layout (floats): x[262144] | e1[16384] | e2[16384] | S[64]
    float* ws = (float*)d_ws;
    float* x  = ws;
    float* e1 = ws + 262144;
    float* e2 = ws + 262144 + 16384;
    float* S  = ws + 262144 + 2 * 16384;

    hipMemsetAsync(S, 0, UNITS * sizeof(float), stream);  // graph-capture-safe
    k1<<<512, 256, 0, stream>>>(inputs, w, aw1, aw2, x, e1, e2, S);
    k2<<<N_NODES, 256, 0, stream>>>(adj, x, e1, e2, S, out);
}

// Round 7
// 117.804 us; speedup vs baseline: 3.1117x; 1.0614x over previous
//
#include <hip/hip_runtime.h>
#include <hip/hip_bf16.h>

// Problem constants (from reference)
#define N_NODES 4096
#define F_IN    128
#define UNITS   64
#define HEADS   4
#define K2_CHUNK 256   // neighbor chunk (typical n ~41, max ~75 -> single chunk)

// ---------------------------------------------------------------------------
// Kernel 1: x = inputs @ w  [N,64], e1 = x @ attn_w1 [N,4], e2 = x @ attn_w2,
//           plus per-block partial column sums of x.
// 512 blocks x 256 threads; each block handles 8 rows -> 2 blocks/CU.
// w staged in NATURAL [k][u] layout: column reads are ds_read_b32 at
// bank = u mod 32 -> 2-way aliasing = free.
// (Best-measured configuration: R2, 118.64 us.)
// ---------------------------------------------------------------------------
__global__ __launch_bounds__(256) void k1(const float* __restrict__ inputs,
                                          const float* __restrict__ w,
                                          const float* __restrict__ aw1,
                                          const float* __restrict__ aw2,
                                          float* __restrict__ x,
                                          float* __restrict__ e1,
                                          float* __restrict__ e2,
                                          float* __restrict__ partial) {
    __shared__ float w_lds[F_IN * UNITS];       // 32 KB, natural [k][u]
    __shared__ float in_lds[8 * F_IN];          // 4 KB
    __shared__ float x_lds[8 * 65];             // padded stride 65
    __shared__ float aw_lds[2 * UNITS * HEADS]; // aw1 then aw2 (2 KB)

    const int t = threadIdx.x;
    const int b = blockIdx.x;
    const int row0 = b * 8;

    // stage w (coalesced float4 copy, no transpose)
    {
        const float4* src = (const float4*)w;
        float4* dst = (float4*)w_lds;
        for (int idx = t; idx < F_IN * UNITS / 4; idx += 256) dst[idx] = src[idx];
    }
    // stage 8 input rows (coalesced float4: 256 float4s, one per thread)
    {
        const float4* src = (const float4*)(inputs + (size_t)row0 * F_IN);
        float4* dst = (float4*)in_lds;
        dst[t] = src[t];
    }
    // stage attention vectors
    if (t < UNITS * HEADS) {
        aw_lds[t] = aw1[t];
        aw_lds[UNITS * HEADS + t] = aw2[t];
    }
    __syncthreads();

    // thread u = t&63 handles column u for rows rg*2, rg*2+1
    const int u = t & 63;
    const int rg = t >> 6;
    float acc0 = 0.f, acc1 = 0.f;
    const float4* r0 = (const float4*)(in_lds + (rg * 2 + 0) * F_IN);
    const float4* r1 = (const float4*)(in_lds + (rg * 2 + 1) * F_IN);
#pragma unroll 8
    for (int c = 0; c < F_IN / 4; c++) {
        const int k4 = c * 4;
        const float w0 = w_lds[(k4 + 0) * UNITS + u];   // 2-way bank alias: free
        const float w1 = w_lds[(k4 + 1) * UNITS + u];
        const float w2 = w_lds[(k4 + 2) * UNITS + u];
        const float w3 = w_lds[(k4 + 3) * UNITS + u];
        float4 a;
        a = r0[c]; acc0 = fmaf(a.w, w3, fmaf(a.z, w2, fmaf(a.y, w1, fmaf(a.x, w0, acc0))));
        a = r1[c]; acc1 = fmaf(a.w, w3, fmaf(a.z, w2, fmaf(a.y, w1, fmaf(a.x, w0, acc1))));
    }
    x_lds[(rg * 2 + 0) * 65 + u] = acc0;
    x_lds[(rg * 2 + 1) * 65 + u] = acc1;
    x[(size_t)(row0 + rg * 2 + 0) * UNITS + u] = acc0;
    x[(size_t)(row0 + rg * 2 + 1) * UNITS + u] = acc1;
    __syncthreads();

    // e1/e2: 8 rows x 4 heads x 2 matrices = 64 tasks
    if (t < 64) {
        const int r = t >> 3;
        const int rem = t & 7;
        const int h = rem & 3;
        const bool first = rem < 4;
        const float* aw = aw_lds + (first ? 0 : UNITS * HEADS);
        float s = 0.f;
#pragma unroll 8
        for (int uu = 0; uu < UNITS; uu++)
            s += x_lds[r * 65 + uu] * aw[uu * HEADS + h];
        (first ? e1 : e2)[(size_t)(row0 + r) * HEADS + h] = s;
    }

    // partial column sums of x over this block's 8 rows
    if (t < 64) {
        float s = 0.f;
#pragma unroll
        for (int r = 0; r < 8; r++) s += x_lds[r * 65 + t];
        partial[b * 64 + t] = s;
    }
}

// ---------------------------------------------------------------------------
// Kernel 1b: S[u] = sum over 512 block-partials (256 threads, 4-way split)
// ---------------------------------------------------------------------------
__global__ __launch_bounds__(256) void k1b(const float* __restrict__ partial,
                                           float* __restrict__ S) {
    __shared__ float red[4][64];
    const int u = threadIdx.x & 63;
    const int q = threadIdx.x >> 6;
    float s = 0.f;
#pragma unroll 8
    for (int b = q; b < 512; b += 4) s += partial[b * 64 + u];
    red[q][u] = s;
    __syncthreads();
    if (threadIdx.x < 64) S[u] = red[0][u] + red[1][u] + red[2][u] + red[3][u];
}

// ---------------------------------------------------------------------------
// Kernel 2: per row i.
//   - ballot-based neighbor compaction (1 LDS atomic per WAVE)
//   - phase A: all 4 head-weights per neighbor computed ONCE (float4 -> LDS),
//     per-thread den partials accumulated here (out of the hot loop)
//   - phase B: the 4 waves split the NEIGHBOR LIST (k = wave, wave+4, ...).
//     Each x row is loaded once per block, each lane carries 4 head
//     accumulators. Inner loop per neighbor: 1 broadcast ds_read_b128 +
//     1 uniform nbr read + 1 coalesced b32 + 4 FMA.
//   - final 4-way cross-wave LDS reduction recombines.
// LDS ~16.3 KB; out[i, h*64+u] = relu((S[u]+acc_h)/(N+den_h)).
// ---------------------------------------------------------------------------
__global__ __launch_bounds__(256) void k2(const float* __restrict__ adj,
                                          const float* __restrict__ x,
                                          const float* __restrict__ e1,
                                          const float* __restrict__ e2,
                                          const float* __restrict__ S,
                                          float* __restrict__ out) {
    __shared__ unsigned short nbr[N_NODES];   // 8 KB — worst case all neighbors
    __shared__ float4 wgt[K2_CHUNK];          // 4 KB — per-neighbor head weights
    __shared__ float red[4][HEADS * UNITS];   // 4 KB — per-wave partial sums
    __shared__ float4 denred[4];              // per-wave den partials
    __shared__ int cnt;

    const int i = blockIdx.x;
    const int t = threadIdx.x;
    const int lane = t & 63;
    const int wid = t >> 6;

    if (t == 0) cnt = 0;
    __syncthreads();

    // scan adjacency row: issue all 4 float4 loads up front (latency overlap)
    const float4* arow = (const float4*)(adj + (size_t)i * N_NODES);
    const float4 v0 = arow[t];
    const float4 v1 = arow[t + 256];
    const float4 v2 = arow[t + 512];
    const float4 v3 = arow[t + 768];

    // ballots are wave-uniform -> live in SGPR pairs
    const unsigned long long b0  = __ballot(v0.x != 0.f);
    const unsigned long long b1  = __ballot(v0.y != 0.f);
    const unsigned long long b2  = __ballot(v0.z != 0.f);
    const unsigned long long b3  = __ballot(v0.w != 0.f);
    const unsigned long long b4  = __ballot(v1.x != 0.f);
    const unsigned long long b5  = __ballot(v1.y != 0.f);
    const unsigned long long b6  = __ballot(v1.z != 0.f);
    const unsigned long long b7  = __ballot(v1.w != 0.f);
    const unsigned long long b8  = __ballot(v2.x != 0.f);
    const unsigned long long b9  = __ballot(v2.y != 0.f);
    const unsigned long long b10 = __ballot(v2.z != 0.f);
    const unsigned long long b11 = __ballot(v2.w != 0.f);
    const unsigned long long b12 = __ballot(v3.x != 0.f);
    const unsigned long long b13 = __ballot(v3.y != 0.f);
    const unsigned long long b14 = __ballot(v3.z != 0.f);
    const unsigned long long b15 = __ballot(v3.w != 0.f);

    const int tot = __popcll(b0) + __popcll(b1) + __popcll(b2) + __popcll(b3)
                  + __popcll(b4) + __popcll(b5) + __popcll(b6) + __popcll(b7)
                  + __popcll(b8) + __popcll(b9) + __popcll(b10) + __popcll(b11)
                  + __popcll(b12) + __popcll(b13) + __popcll(b14) + __popcll(b15);

    int wbase = 0;
    if (lane == 0) wbase = atomicAdd(&cnt, tot);   // ONE atomic per wave
    wbase = __shfl(wbase, 0);

    const unsigned long long lt = (1ull << lane) - 1ull;
    {
        int off = wbase;
        const int g0 = t * 4, g1 = (t + 256) * 4, g2 = (t + 512) * 4, g3 = (t + 768) * 4;
        if (v0.x != 0.f) nbr[off + __popcll(b0  & lt)] = (unsigned short)(g0 + 0); off += __popcll(b0);
        if (v0.y != 0.f) nbr[off + __popcll(b1  & lt)] = (unsigned short)(g0 + 1); off += __popcll(b1);
        if (v0.z != 0.f) nbr[off + __popcll(b2  & lt)] = (unsigned short)(g0 + 2); off += __popcll(b2);
        if (v0.w != 0.f) nbr[off + __popcll(b3  & lt)] = (unsigned short)(g0 + 3); off += __popcll(b3);
        if (v1.x != 0.f) nbr[off + __popcll(b4  & lt)] = (unsigned short)(g1 + 0); off += __popcll(b4);
        if (v1.y != 0.f) nbr[off + __popcll(b5  & lt)] = (unsigned short)(g1 + 1); off += __popcll(b5);
        if (v1.z != 0.f) nbr[off + __popcll(b6  & lt)] = (unsigned short)(g1 + 2); off += __popcll(b6);
        if (v1.w != 0.f) nbr[off + __popcll(b7  & lt)] = (unsigned short)(g1 + 3); off += __popcll(b7);
        if (v2.x != 0.f) nbr[off + __popcll(b8  & lt)] = (unsigned short)(g2 + 0); off += __popcll(b8);
        if (v2.y != 0.f) nbr[off + __popcll(b9  & lt)] = (unsigned short)(g2 + 1); off += __popcll(b9);
        if (v2.z != 0.f) nbr[off + __popcll(b10 & lt)] = (unsigned short)(g2 + 2); off += __popcll(b10);
        if (v2.w != 0.f) nbr[off + __popcll(b11 & lt)] = (unsigned short)(g2 + 3); off += __popcll(b11);
        if (v3.x != 0.f) nbr[off + __popcll(b12 & lt)] = (unsigned short)(g3 + 0); off += __popcll(b12);
        if (v3.y != 0.f) nbr[off + __popcll(b13 & lt)] = (unsigned short)(g3 + 1); off += __popcll(b13);
        if (v3.z != 0.f) nbr[off + __popcll(b14 & lt)] = (unsigned short)(g3 + 2); off += __popcll(b14);
        if (v3.w != 0.f) nbr[off + __popcll(b15 & lt)] = (unsigned short)(g3 + 3); off += __popcll(b15);
    }
    __syncthreads();

    const int n = cnt;
    const float4 e1v = *(const float4*)(e1 + (size_t)i * HEADS);

    float a0 = 0.f, a1 = 0.f, a2 = 0.f, a3 = 0.f;   // per-head accumulators
    float4 dpart = make_float4(0.f, 0.f, 0.f, 0.f); // per-thread den partials

    for (int base = 0; base < n; base += K2_CHUNK) {
        const int m = min(n - base, K2_CHUNK);

        // phase A: weights for this chunk, one thread per neighbor
        for (int k = t; k < m; k += 256) {
            const int j = nbr[base + k];
            const float4 e2v = *(const float4*)(e2 + (size_t)j * HEADS);
            float4 wv;
            wv.x = __expf(fmaxf(e1v.x + e2v.x, 0.f)) - 1.f;
            wv.y = __expf(fmaxf(e1v.y + e2v.y, 0.f)) - 1.f;
            wv.z = __expf(fmaxf(e1v.z + e2v.z, 0.f)) - 1.f;
            wv.w = __expf(fmaxf(e1v.w + e2v.w, 0.f)) - 1.f;
            wgt[k] = wv;
            dpart.x += wv.x; dpart.y += wv.y; dpart.z += wv.z; dpart.w += wv.w;
        }
        __syncthreads();

        // phase B: waves split the neighbor list; x row loaded once per block
#pragma unroll 4
        for (int k = wid; k < m; k += 4) {
            const float4 p = wgt[k];                    // broadcast ds_read_b128
            const int j = nbr[base + k];                // uniform LDS read
            const float xv = x[(j << 6) + lane];        // coalesced 256 B, L1/L2-hit
            a0 = fmaf(p.x, xv, a0);
            a1 = fmaf(p.y, xv, a1);
            a2 = fmaf(p.z, xv, a2);
            a3 = fmaf(p.w, xv, a3);
        }
        __syncthreads();   // protect wgt before next chunk overwrites
    }

    // wave-reduce den partials (once, outside the hot loop)
    dpart.x += __shfl_xor(dpart.x, 32); dpart.y += __shfl_xor(dpart.y, 32);
    dpart.z += __shfl_xor(dpart.z, 32); dpart.w += __shfl_xor(dpart.w, 32);
    dpart.x += __shfl_xor(dpart.x, 16); dpart.y += __shfl_xor(dpart.y, 16);
    dpart.z += __shfl_xor(dpart.z, 16); dpart.w += __shfl_xor(dpart.w, 16);
    dpart.x += __shfl_xor(dpart.x, 8);  dpart.y += __shfl_xor(dpart.y, 8);
    dpart.z += __shfl_xor(dpart.z, 8);  dpart.w += __shfl_xor(dpart.w, 8);
    dpart.x += __shfl_xor(dpart.x, 4);  dpart.y += __shfl_xor(dpart.y, 4);
    dpart.z += __shfl_xor(dpart.z, 4);  dpart.w += __shfl_xor(dpart.w, 4);
    dpart.x += __shfl_xor(dpart.x, 2);  dpart.y += __shfl_xor(dpart.y, 2);
    dpart.z += __shfl_xor(dpart.z, 2);  dpart.w += __shfl_xor(dpart.w, 2);
    dpart.x += __shfl_xor(dpart.x, 1);  dpart.y += __shfl_xor(dpart.y, 1);
    dpart.z += __shfl_xor(dpart.z, 1);  dpart.w += __shfl_xor(dpart.w, 1);

    // per-wave partials -> LDS
    red[wid][0 * 64 + lane] = a0;
    red[wid][1 * 64 + lane] = a1;
    red[wid][2 * 64 + lane] = a2;
    red[wid][3 * 64 + lane] = a3;
    if (lane == 0) denred[wid] = dpart;
    __syncthreads();

    // thread t = (h, u): recombine 4 wave-partials
    const int h = wid;         // output head = wave id
    const int u = lane;
    const float accsum = red[0][h * 64 + u] + red[1][h * 64 + u]
                       + red[2][h * 64 + u] + red[3][h * 64 + u];
    const float* d0 = (const float*)&denred[0];
    const float* d1 = (const float*)&denred[1];
    const float* d2 = (const float*)&denred[2];
    const float* d3 = (const float*)&denred[3];
    const float den = d0[h] + d1[h] + d2[h] + d3[h];

    const float numer = S[u] + accsum;
    const float denom = (float)N_NODES + den;
    out[(size_t)i * (HEADS * UNITS) + t] = fmaxf(numer / denom, 0.f);
}

// ---------------------------------------------------------------------------
extern "C" void kernel_launch(void* const* d_in, const int* in_sizes, int n_in,
                              void* d_out, int out_size, void* d_ws, size_t ws_size,
                              hipStream_t stream) {
    const float* inputs = (const float*)d_in[0];
    const float* adj    = (const float*)d_in[1];
    const float* w      = (const float*)d_in[2];
    const float* aw1    = (const float*)d_in[3];
    const float* aw2    = (const float*)d_in[4];
    float* out = (float*)d_out;

    // workspace layout (floats): x[262144] | e1[16384] | e2[16384] | partial[32768] | S[64]
    float* ws = (float*)d_ws;
    float* x       = ws;
    float* e1      = ws + 262144;
    float* e2      = ws + 262144 + 16384;
    float* partial = ws + 262144 + 2 * 16384;
    float* S       = ws + 262144 + 2 * 16384 + 32768;

    k1<<<512, 256, 0, stream>>>(inputs, w, aw1, aw2, x, e1, e2, partial);
    k1b<<<1, 256, 0, stream>>>(partial, S);
    k2<<<N_NODES, 256, 0, stream>>>(adj, x, e1, e2, S, out);
}